// Round 8
// baseline (334.867 us; speedup 1.0000x reference)
//
#include <hip/hip_runtime.h>

typedef __attribute__((ext_vector_type(4)))  float f32x4;
typedef __attribute__((ext_vector_type(16))) float f32x16;
typedef __attribute__((ext_vector_type(8)))  short short8;
typedef __attribute__((ext_vector_type(4)))  unsigned short u16x4;
typedef __attribute__((ext_vector_type(4)))  unsigned int u32x4;
typedef __attribute__((ext_vector_type(2)))  unsigned int u32x2;

// float -> bf16, round-to-nearest-even
static __device__ __forceinline__ unsigned short f2bf(float f) {
    unsigned int u = __float_as_uint(f);
    unsigned int r = (u + 0x7FFFu + ((u >> 16) & 1u)) >> 16;
    return (unsigned short)r;
}

#if __has_builtin(__builtin_amdgcn_exp2f)
#define EXP2(x) __builtin_amdgcn_exp2f(x)
#else
#define EXP2(x) exp2f(x)
#endif

// v_permlane32_swap_b32: a' = {lo: a.lo, hi: b.lo}, b' = {lo: a.hi, hi: b.hi}
static __device__ __forceinline__ void swap32(unsigned int& a, unsigned int& b) {
#if __has_builtin(__builtin_amdgcn_permlane32_swap)
    u32x2 r = __builtin_amdgcn_permlane32_swap(a, b, false, false);
    a = r[0]; b = r[1];
#else
    asm("v_permlane32_swap_b32 %0, %1" : "+v"(a), "+v"(b));
#endif
}

// 32^-0.5 * log2(e): q-scale with exp2 conversion folded in
#define SCALE2Q 0.25503487756f

// ---------------------------------------------------------------------------
// Kernel 1: pack weights to bf16. W[320][256]: rows 0..31 = scale2q*w_qk(q),
// rows 32..63 = w_qk(k), rows 64..319 = w_v.
// ---------------------------------------------------------------------------
__global__ void prep_w_kernel(const float* __restrict__ wqk,
                              const float* __restrict__ wv,
                              unsigned short* __restrict__ W) {
    int idx = blockIdx.x * 256 + threadIdx.x;
    int o = idx >> 8, c = idx & 255;
    float v;
    if (o < 64) { v = wqk[o * 256 + c]; if (o < 32) v *= SCALE2Q; }
    else        { v = wv[(o - 64) * 256 + c]; }
    W[idx] = f2bf(v);
}

// ---------------------------------------------------------------------------
// Kernel 2: xT[b][s][c] = bf16(x[b][c][s]).  64x64 tiles via LDS.
// ---------------------------------------------------------------------------
__global__ __launch_bounds__(256) void transpose_kernel(
        const float* __restrict__ x, unsigned short* __restrict__ xT) {
    __shared__ unsigned short tile[64][66];
    int b = blockIdx.x & 7;
    int rem = blockIdx.x >> 3;
    int ct = rem >> 6, st = rem & 63;
    int s0 = st * 64, c0 = ct * 64;
    int tid = threadIdx.x;
    int ss = tid & 63, cq = tid >> 6;
#pragma unroll
    for (int p = 0; p < 16; ++p) {
        int cc = p * 4 + cq;
        float v = x[(size_t)(b * 256 + c0 + cc) * 4096 + s0 + ss];
        tile[ss][cc] = f2bf(v);
    }
    __syncthreads();
#pragma unroll
    for (int p = 0; p < 8; ++p) {
        int idx = p * 256 + tid;
        int sr = idx >> 5, jj = idx & 31;
        unsigned int val = *(const unsigned int*)&tile[sr][jj * 2];
        *(unsigned int*)(xT + (size_t)(b * 4096 + s0 + sr) * 256 + c0 + jj * 2) = val;
    }
}

// ---------------------------------------------------------------------------
// Kernel 3: projection GEMM (MFMA 16x16x32, no LDS).
// ---------------------------------------------------------------------------
__global__ __launch_bounds__(256) void proj_kernel(
        const unsigned short* __restrict__ W,    // [320][256]
        const unsigned short* __restrict__ xT,   // [8][4096][256]
        unsigned short* __restrict__ qkT,        // [8][4096][64]
        unsigned short* __restrict__ vbuf) {     // [8][256][4096]
    const int b  = blockIdx.x & 7;
    const int sb = blockIdx.x >> 3;
    const int s0 = sb * 64;
    const int tid = threadIdx.x;
    const int w = tid >> 6, l = tid & 63;
    const int lg = l >> 4, ll = l & 15;
    const size_t xbase = (size_t)b * 4096 * 256;

    f32x4 acc[5][4];
#pragma unroll
    for (int ot = 0; ot < 5; ++ot)
#pragma unroll
        for (int st = 0; st < 4; ++st) acc[ot][st] = (f32x4)0.0f;

    for (int k0 = 0; k0 < 256; k0 += 32) {
        short8 bf[4], af[5];
#pragma unroll
        for (int st = 0; st < 4; ++st)
            bf[st] = *(const short8*)(xT + xbase + (size_t)(s0 + st * 16 + ll) * 256 + k0 + lg * 8);
#pragma unroll
        for (int ot = 0; ot < 5; ++ot)
            af[ot] = *(const short8*)(W + (size_t)(80 * w + ot * 16 + ll) * 256 + k0 + lg * 8);
#pragma unroll
        for (int ot = 0; ot < 5; ++ot)
#pragma unroll
            for (int st = 0; st < 4; ++st)
                acc[ot][st] = __builtin_amdgcn_mfma_f32_16x16x32_bf16(af[ot], bf[st], acc[ot][st], 0, 0, 0);
    }
#pragma unroll
    for (int ot = 0; ot < 5; ++ot) {
        int o0 = 80 * w + ot * 16 + lg * 4;
#pragma unroll
        for (int st = 0; st < 4; ++st) {
            int s = s0 + st * 16 + ll;
            if (o0 < 64) {
                u16x4 pk;
#pragma unroll
                for (int i = 0; i < 4; ++i) pk[i] = f2bf(acc[ot][st][i]);
                *(u16x4*)(qkT + (size_t)b * 4096 * 64 + (size_t)s * 64 + o0) = pk;
            } else {
#pragma unroll
                for (int i = 0; i < 4; ++i)
                    vbuf[(size_t)b * 256 * 4096 + (size_t)(o0 - 64 + i) * 4096 + s] = f2bf(acc[ot][st][i]);
            }
        }
    }
}

// ---------------------------------------------------------------------------
// Kernel 4: attention, fully in-register softmax, ZERO inner barriers.
// grid 512 = 8 b x 32 q-tiles(128) x 2 ch-halves; 256 thr = 4 waves.
// Wave w: 32 q-rows (s0+32w..+32) x 128 channels (chalf*128..+128).
// Per 64-key tile: swapped QK mfma_32x32x16(K,Q) -> P lane-local ->
// exp2 -> cvt_pk + permlane32_swap (T12) -> PV A-frags in-register ->
// 16x PV MFMA. K/V reloaded into same regs after last use (anti-dep gives
// ~1 tile of L2-latency slack). LDS: only lsum[128] + one final barrier.
// ---------------------------------------------------------------------------
__global__ __launch_bounds__(256, 2) void attn_kernel(
        const unsigned short* __restrict__ qkT,  // [8][4096][64] (q|k)
        const unsigned short* __restrict__ vbuf, // [8][256][4096]
        const float* __restrict__ x,             // [8][256][4096]
        const float* __restrict__ gamma,
        float* __restrict__ out) {
    __shared__ float lsum_lds[128];

    const int b     = blockIdx.x & 7;        // batch == XCD (L2 pinning)
    const int sb    = (blockIdx.x >> 3) & 31;
    const int chalf = blockIdx.x >> 8;
    const int s0    = sb * 128;
    const int w     = threadIdx.x >> 6;      // 0..3
    const int l     = threadIdx.x & 63;
    const int l5    = l >> 5, l31 = l & 31;

    const size_t qk_base = (size_t)b * 4096 * 64;
    const size_t bx_base = (size_t)b * 256 * 4096;
    const unsigned short* kb = qkT + qk_base;
    const int chbase = 128 * chalf;

    // Q frags: B-operand, col = q = s0+32w+l31, k = lat 8*l5+j (+16)
    const unsigned short* qrow = qkT + qk_base + (size_t)(s0 + 32 * w + l31) * 64;
    const short8 qf0 = *(const short8*)(qrow + 8 * l5);
    const short8 qf1 = *(const short8*)(qrow + 16 + 8 * l5);

    // V row pointers: B-operand, col = ch = chbase+32ct+l31, k = 8*l5+j
    const unsigned short* vr[4];
#pragma unroll
    for (int ct = 0; ct < 4; ++ct)
        vr[ct] = vbuf + bx_base + (size_t)(chbase + 32 * ct + l31) * 4096 + 8 * l5;

    f32x16 acc[4];
#pragma unroll
    for (int ct = 0; ct < 4; ++ct) acc[ct] = (f32x16)0.0f;
    float psum = 0.f;
    const f32x16 z16 = (f32x16)0.0f;

    // K frags: A-operand, row = key = 32*kt+l31, k = lat 16*h+8*l5+j
    short8 kf[2][2];
#pragma unroll
    for (int kt = 0; kt < 2; ++kt)
#pragma unroll
        for (int h = 0; h < 2; ++h)
            kf[kt][h] = *(const short8*)(kb + (size_t)(32 * kt + l31) * 64 + 32 + 16 * h + 8 * l5);
    short8 vf[4][4];
#pragma unroll
    for (int ct = 0; ct < 4; ++ct)
#pragma unroll
        for (int ks = 0; ks < 4; ++ks)
            vf[ct][ks] = *(const short8*)(vr[ct] + 16 * ks);

// exp2 the 16 regs of DD (keys (r&3)+8(r>>2)+4l5), pack to bf16, permlane-swap
// into two PV A-frags: PLO = keys [base,base+16), PHI = [base+16,base+32).
#define EXPPACK(DD, PLO, PHI)                                                  \
    {                                                                          \
        float e0 = EXP2((DD)[0]),   e1 = EXP2((DD)[1]);                        \
        float e2 = EXP2((DD)[2]),   e3 = EXP2((DD)[3]);                        \
        float e4 = EXP2((DD)[4]),   e5 = EXP2((DD)[5]);                        \
        float e6 = EXP2((DD)[6]),   e7 = EXP2((DD)[7]);                        \
        float e8 = EXP2((DD)[8]),   e9 = EXP2((DD)[9]);                        \
        float e10 = EXP2((DD)[10]), e11 = EXP2((DD)[11]);                      \
        float e12 = EXP2((DD)[12]), e13 = EXP2((DD)[13]);                      \
        float e14 = EXP2((DD)[14]), e15 = EXP2((DD)[15]);                      \
        psum += (((e0 + e1) + (e2 + e3)) + ((e4 + e5) + (e6 + e7)))            \
              + (((e8 + e9) + (e10 + e11)) + ((e12 + e13) + (e14 + e15)));     \
        unsigned int c0, c1, c2, c3;                                           \
        asm("v_cvt_pk_bf16_f32 %0, %1, %2" : "=v"(c0) : "v"(e0), "v"(e1));     \
        asm("v_cvt_pk_bf16_f32 %0, %1, %2" : "=v"(c1) : "v"(e2), "v"(e3));     \
        asm("v_cvt_pk_bf16_f32 %0, %1, %2" : "=v"(c2) : "v"(e4), "v"(e5));     \
        asm("v_cvt_pk_bf16_f32 %0, %1, %2" : "=v"(c3) : "v"(e6), "v"(e7));     \
        swap32(c0, c2); swap32(c1, c3);                                        \
        { u32x4 t_; t_[0] = c0; t_[1] = c1; t_[2] = c2; t_[3] = c3;            \
          PLO = *(short8*)&t_; }                                               \
        unsigned int d0, d1, d2, d3;                                           \
        asm("v_cvt_pk_bf16_f32 %0, %1, %2" : "=v"(d0) : "v"(e8), "v"(e9));     \
        asm("v_cvt_pk_bf16_f32 %0, %1, %2" : "=v"(d1) : "v"(e10), "v"(e11));   \
        asm("v_cvt_pk_bf16_f32 %0, %1, %2" : "=v"(d2) : "v"(e12), "v"(e13));   \
        asm("v_cvt_pk_bf16_f32 %0, %1, %2" : "=v"(d3) : "v"(e14), "v"(e15));   \
        swap32(d0, d2); swap32(d1, d3);                                        \
        { u32x4 t_; t_[0] = d0; t_[1] = d1; t_[2] = d2; t_[3] = d3;            \
          PHI = *(short8*)&t_; }                                               \
    }

    for (int t = 0; t < 64; ++t) {
        const int tn = ((t + 1) & 63) * 64;
        // ---- swapped QK^T: D[key][q] ----
        f32x16 dd0 = __builtin_amdgcn_mfma_f32_32x32x16_bf16(kf[0][0], qf0, z16, 0, 0, 0);
        dd0 = __builtin_amdgcn_mfma_f32_32x32x16_bf16(kf[0][1], qf1, dd0, 0, 0, 0);
        f32x16 dd1 = __builtin_amdgcn_mfma_f32_32x32x16_bf16(kf[1][0], qf0, z16, 0, 0, 0);
        dd1 = __builtin_amdgcn_mfma_f32_32x32x16_bf16(kf[1][1], qf1, dd1, 0, 0, 0);
        // reload K for next tile (anti-dep: issues after QK, lands in ~1 tile)
#pragma unroll
        for (int kt = 0; kt < 2; ++kt)
#pragma unroll
            for (int h = 0; h < 2; ++h)
                kf[kt][h] = *(const short8*)(kb + (size_t)(tn + 32 * kt + l31) * 64 + 32 + 16 * h + 8 * l5);
        // ---- softmax numerator in-register ----
        short8 pa0, pa1, pa2, pa3;
        EXPPACK(dd0, pa0, pa1)
        EXPPACK(dd1, pa2, pa3)
        // ---- PV with rolling V reload ----
#pragma unroll
        for (int ct = 0; ct < 4; ++ct)
            acc[ct] = __builtin_amdgcn_mfma_f32_32x32x16_bf16(pa0, vf[ct][0], acc[ct], 0, 0, 0);
#pragma unroll
        for (int ct = 0; ct < 4; ++ct)
            vf[ct][0] = *(const short8*)(vr[ct] + tn);
#pragma unroll
        for (int ct = 0; ct < 4; ++ct)
            acc[ct] = __builtin_amdgcn_mfma_f32_32x32x16_bf16(pa1, vf[ct][1], acc[ct], 0, 0, 0);
#pragma unroll
        for (int ct = 0; ct < 4; ++ct)
            vf[ct][1] = *(const short8*)(vr[ct] + tn + 16);
#pragma unroll
        for (int ct = 0; ct < 4; ++ct)
            acc[ct] = __builtin_amdgcn_mfma_f32_32x32x16_bf16(pa2, vf[ct][2], acc[ct], 0, 0, 0);
#pragma unroll
        for (int ct = 0; ct < 4; ++ct)
            vf[ct][2] = *(const short8*)(vr[ct] + tn + 32);
#pragma unroll
        for (int ct = 0; ct < 4; ++ct)
            acc[ct] = __builtin_amdgcn_mfma_f32_32x32x16_bf16(pa3, vf[ct][3], acc[ct], 0, 0, 0);
#pragma unroll
        for (int ct = 0; ct < 4; ++ct)
            vf[ct][3] = *(const short8*)(vr[ct] + tn + 48);
    }
#undef EXPPACK

    // ---- row-sum: lane covers half of q=l31's keys; partner is l^32 ----
    psum += __shfl_xor(psum, 32);
    if (l5 == 0) lsum_lds[32 * w + l31] = psum;
    __syncthreads();

    // ---- epilogue: out = gamma*acc/lsum + x ----
    const float g = gamma[0];
#pragma unroll
    for (int rq = 0; rq < 4; ++rq) {
        // acc D row (q-local) = (r&3) + 8*(r>>2) + 4*l5, r = 4*rq+m
        f32x4 ls = *(const f32x4*)&lsum_lds[32 * w + 8 * rq + 4 * l5];
        f32x4 gi;
#pragma unroll
        for (int m = 0; m < 4; ++m) gi[m] = g / ls[m];
        const int srow = s0 + 32 * w + 8 * rq + 4 * l5;
#pragma unroll
        for (int ct = 0; ct < 4; ++ct) {
            size_t off = bx_base + (size_t)(chbase + 32 * ct + l31) * 4096 + srow;
            f32x4 xv = *(const f32x4*)(x + off);
            f32x4 o;
#pragma unroll
            for (int m = 0; m < 4; ++m)
                o[m] = gi[m] * acc[ct][4 * rq + m] + xv[m];
            *(f32x4*)(out + off) = o;
        }
    }
}

// ---------------------------------------------------------------------------
extern "C" void kernel_launch(void* const* d_in, const int* in_sizes, int n_in,
                              void* d_out, int out_size, void* d_ws, size_t ws_size,
                              hipStream_t stream) {
    const float* x     = (const float*)d_in[0];
    const float* wqk   = (const float*)d_in[1];
    const float* wv    = (const float*)d_in[2];
    const float* gamma = (const float*)d_in[3];
    float* out = (float*)d_out;

    char* ws = (char*)d_ws;
    unsigned short* W    = (unsigned short*)(ws);                       // 160 KiB
    unsigned short* qkT  = (unsigned short*)(ws + 163840);              // 4 MiB
    unsigned short* xT   = (unsigned short*)(ws + 163840 + 4194304);    // 16 MiB
    unsigned short* vbuf = (unsigned short*)(ws + 163840 + 4194304 + 16777216); // 16 MiB

    hipLaunchKernelGGL(prep_w_kernel,    dim3(320),  dim3(256), 0, stream, wqk, wv, W);
    hipLaunchKernelGGL(transpose_kernel, dim3(2048), dim3(256), 0, stream, x, xT);
    hipLaunchKernelGGL(proj_kernel,      dim3(512),  dim3(256), 0, stream, W, xT, qkT, vbuf);
    hipLaunchKernelGGL(attn_kernel,      dim3(512),  dim3(256), 0, stream, qkT, vbuf, x, gamma, out);
}

// Round 9
// 331.637 us; speedup vs baseline: 1.0097x; 1.0097x over previous
//
#include <hip/hip_runtime.h>

typedef __attribute__((ext_vector_type(4)))  float f32x4;
typedef __attribute__((ext_vector_type(16))) float f32x16;
typedef __attribute__((ext_vector_type(8)))  short short8;
typedef __attribute__((ext_vector_type(4)))  unsigned short u16x4;
typedef __attribute__((ext_vector_type(4)))  unsigned int u32x4;
typedef __attribute__((ext_vector_type(2)))  unsigned int u32x2;

// float -> bf16, round-to-nearest-even
static __device__ __forceinline__ unsigned short f2bf(float f) {
    unsigned int u = __float_as_uint(f);
    unsigned int r = (u + 0x7FFFu + ((u >> 16) & 1u)) >> 16;
    return (unsigned short)r;
}

#if __has_builtin(__builtin_amdgcn_exp2f)
#define EXP2(x) __builtin_amdgcn_exp2f(x)
#else
#define EXP2(x) exp2f(x)
#endif

// v_permlane32_swap_b32: a' = {lo: a.lo, hi: b.lo}, b' = {lo: a.hi, hi: b.hi}
static __device__ __forceinline__ void swap32(unsigned int& a, unsigned int& b) {
#if __has_builtin(__builtin_amdgcn_permlane32_swap)
    u32x2 r = __builtin_amdgcn_permlane32_swap(a, b, false, false);
    a = r[0]; b = r[1];
#else
    asm("v_permlane32_swap_b32 %0, %1" : "+v"(a), "+v"(b));
#endif
}

// 32^-0.5 * log2(e): q-scale with exp2 conversion folded in
#define SCALE2Q 0.25503487756f

// ---------------------------------------------------------------------------
// Kernel 1: pack weights to bf16. W[320][256]: rows 0..31 = scale2q*w_qk(q),
// rows 32..63 = w_qk(k), rows 64..319 = w_v.
// ---------------------------------------------------------------------------
__global__ void prep_w_kernel(const float* __restrict__ wqk,
                              const float* __restrict__ wv,
                              unsigned short* __restrict__ W) {
    int idx = blockIdx.x * 256 + threadIdx.x;
    int o = idx >> 8, c = idx & 255;
    float v;
    if (o < 64) { v = wqk[o * 256 + c]; if (o < 32) v *= SCALE2Q; }
    else        { v = wv[(o - 64) * 256 + c]; }
    W[idx] = f2bf(v);
}

// ---------------------------------------------------------------------------
// Kernel 2: xT[b][s][c] = bf16(x[b][c][s]).  64x64 tiles via LDS.
// ---------------------------------------------------------------------------
__global__ __launch_bounds__(256) void transpose_kernel(
        const float* __restrict__ x, unsigned short* __restrict__ xT) {
    __shared__ unsigned short tile[64][66];
    int b = blockIdx.x & 7;
    int rem = blockIdx.x >> 3;
    int ct = rem >> 6, st = rem & 63;
    int s0 = st * 64, c0 = ct * 64;
    int tid = threadIdx.x;
    int ss = tid & 63, cq = tid >> 6;
#pragma unroll
    for (int p = 0; p < 16; ++p) {
        int cc = p * 4 + cq;
        float v = x[(size_t)(b * 256 + c0 + cc) * 4096 + s0 + ss];
        tile[ss][cc] = f2bf(v);
    }
    __syncthreads();
#pragma unroll
    for (int p = 0; p < 8; ++p) {
        int idx = p * 256 + tid;
        int sr = idx >> 5, jj = idx & 31;
        unsigned int val = *(const unsigned int*)&tile[sr][jj * 2];
        *(unsigned int*)(xT + (size_t)(b * 4096 + s0 + sr) * 256 + c0 + jj * 2) = val;
    }
}

// ---------------------------------------------------------------------------
// Kernel 3: projection GEMM (MFMA 16x16x32, no LDS).
// ---------------------------------------------------------------------------
__global__ __launch_bounds__(256) void proj_kernel(
        const unsigned short* __restrict__ W,    // [320][256]
        const unsigned short* __restrict__ xT,   // [8][4096][256]
        unsigned short* __restrict__ qkT,        // [8][4096][64]
        unsigned short* __restrict__ vbuf) {     // [8][256][4096]
    const int b  = blockIdx.x & 7;
    const int sb = blockIdx.x >> 3;
    const int s0 = sb * 64;
    const int tid = threadIdx.x;
    const int w = tid >> 6, l = tid & 63;
    const int lg = l >> 4, ll = l & 15;
    const size_t xbase = (size_t)b * 4096 * 256;

    f32x4 acc[5][4];
#pragma unroll
    for (int ot = 0; ot < 5; ++ot)
#pragma unroll
        for (int st = 0; st < 4; ++st) acc[ot][st] = (f32x4)0.0f;

    for (int k0 = 0; k0 < 256; k0 += 32) {
        short8 bf[4], af[5];
#pragma unroll
        for (int st = 0; st < 4; ++st)
            bf[st] = *(const short8*)(xT + xbase + (size_t)(s0 + st * 16 + ll) * 256 + k0 + lg * 8);
#pragma unroll
        for (int ot = 0; ot < 5; ++ot)
            af[ot] = *(const short8*)(W + (size_t)(80 * w + ot * 16 + ll) * 256 + k0 + lg * 8);
#pragma unroll
        for (int ot = 0; ot < 5; ++ot)
#pragma unroll
            for (int st = 0; st < 4; ++st)
                acc[ot][st] = __builtin_amdgcn_mfma_f32_16x16x32_bf16(af[ot], bf[st], acc[ot][st], 0, 0, 0);
    }
#pragma unroll
    for (int ot = 0; ot < 5; ++ot) {
        int o0 = 80 * w + ot * 16 + lg * 4;
#pragma unroll
        for (int st = 0; st < 4; ++st) {
            int s = s0 + st * 16 + ll;
            if (o0 < 64) {
                u16x4 pk;
#pragma unroll
                for (int i = 0; i < 4; ++i) pk[i] = f2bf(acc[ot][st][i]);
                *(u16x4*)(qkT + (size_t)b * 4096 * 64 + (size_t)s * 64 + o0) = pk;
            } else {
#pragma unroll
                for (int i = 0; i < 4; ++i)
                    vbuf[(size_t)b * 256 * 4096 + (size_t)(o0 - 64 + i) * 4096 + s] = f2bf(acc[ot][st][i]);
            }
        }
    }
}

// ---------------------------------------------------------------------------
// Kernel 4: attention, fully in-register softmax, ZERO inner barriers.
// grid 512 = 8 b x 32 q-tiles(128) x 2 ch-halves; 256 thr = 4 waves.
// Wave w: 32 q-rows x 128 channels. Swapped QK mfma(K,Q) -> lane-local P ->
// exp2 -> cvt_pk + permlane32_swap -> PV A-frags, all in registers
// (__builtin_bit_cast only -- NO address-of-local, which caused R8's
// scratch demotion at VGPR_Count=92). K/V rolling reload with 1-tile slack.
// ---------------------------------------------------------------------------
__global__ __launch_bounds__(256, 2) void attn_kernel(
        const unsigned short* __restrict__ qkT,  // [8][4096][64] (q|k)
        const unsigned short* __restrict__ vbuf, // [8][256][4096]
        const float* __restrict__ x,             // [8][256][4096]
        const float* __restrict__ gamma,
        float* __restrict__ out) {
    __shared__ float lsum_lds[128];

    const int b     = blockIdx.x & 7;        // batch == XCD (L2 pinning)
    const int sb    = (blockIdx.x >> 3) & 31;
    const int chalf = blockIdx.x >> 8;
    const int s0    = sb * 128;
    const int w     = threadIdx.x >> 6;      // 0..3
    const int l     = threadIdx.x & 63;
    const int l5    = l >> 5, l31 = l & 31;

    const size_t qk_base = (size_t)b * 4096 * 64;
    const size_t bx_base = (size_t)b * 256 * 4096;
    const unsigned short* kb = qkT + qk_base;
    const int chbase = 128 * chalf;

    // Q frags: B-operand, col = q = s0+32w+l31, k = lat 8*l5+j (+16)
    const unsigned short* qrow = qkT + qk_base + (size_t)(s0 + 32 * w + l31) * 64;
    const short8 qf0 = *(const short8*)(qrow + 8 * l5);
    const short8 qf1 = *(const short8*)(qrow + 16 + 8 * l5);

    // V row pointers: B-operand, col = ch = chbase+32ct+l31, k = 8*l5+j
    const unsigned short* vr0 = vbuf + bx_base + (size_t)(chbase +  0 + l31) * 4096 + 8 * l5;
    const unsigned short* vr1 = vbuf + bx_base + (size_t)(chbase + 32 + l31) * 4096 + 8 * l5;
    const unsigned short* vr2 = vbuf + bx_base + (size_t)(chbase + 64 + l31) * 4096 + 8 * l5;
    const unsigned short* vr3 = vbuf + bx_base + (size_t)(chbase + 96 + l31) * 4096 + 8 * l5;

    f32x16 acc0 = (f32x16)0.0f, acc1 = (f32x16)0.0f;
    f32x16 acc2 = (f32x16)0.0f, acc3 = (f32x16)0.0f;
    float psum = 0.f;
    const f32x16 z16 = (f32x16)0.0f;

    // K frags: A-operand, row = key = 32*kt+l31, k = lat 16*h+8*l5+j
    short8 kf00 = *(const short8*)(kb + (size_t)(l31) * 64 + 32 + 8 * l5);
    short8 kf01 = *(const short8*)(kb + (size_t)(l31) * 64 + 32 + 16 + 8 * l5);
    short8 kf10 = *(const short8*)(kb + (size_t)(32 + l31) * 64 + 32 + 8 * l5);
    short8 kf11 = *(const short8*)(kb + (size_t)(32 + l31) * 64 + 32 + 16 + 8 * l5);

    short8 vf0[4], vf1[4], vf2[4], vf3[4];
#pragma unroll
    for (int ks = 0; ks < 4; ++ks) {
        vf0[ks] = *(const short8*)(vr0 + 16 * ks);
        vf1[ks] = *(const short8*)(vr1 + 16 * ks);
        vf2[ks] = *(const short8*)(vr2 + 16 * ks);
        vf3[ks] = *(const short8*)(vr3 + 16 * ks);
    }

// exp2 the 16 regs of DD, pack to bf16 (cvt_pk), permlane-swap into two PV
// A-frags: PLO = keys [base,+16), PHI = [base+16,+32). No address-of-local.
#define EXPPACK(DD, PLO, PHI)                                                  \
    {                                                                          \
        float e0 = EXP2((DD)[0]),   e1 = EXP2((DD)[1]);                        \
        float e2 = EXP2((DD)[2]),   e3 = EXP2((DD)[3]);                        \
        float e4 = EXP2((DD)[4]),   e5 = EXP2((DD)[5]);                        \
        float e6 = EXP2((DD)[6]),   e7 = EXP2((DD)[7]);                        \
        float e8 = EXP2((DD)[8]),   e9 = EXP2((DD)[9]);                        \
        float e10 = EXP2((DD)[10]), e11 = EXP2((DD)[11]);                      \
        float e12 = EXP2((DD)[12]), e13 = EXP2((DD)[13]);                      \
        float e14 = EXP2((DD)[14]), e15 = EXP2((DD)[15]);                      \
        psum += (((e0 + e1) + (e2 + e3)) + ((e4 + e5) + (e6 + e7)))            \
              + (((e8 + e9) + (e10 + e11)) + ((e12 + e13) + (e14 + e15)));     \
        unsigned int c0, c1, c2, c3;                                           \
        asm("v_cvt_pk_bf16_f32 %0, %1, %2" : "=v"(c0) : "v"(e0), "v"(e1));     \
        asm("v_cvt_pk_bf16_f32 %0, %1, %2" : "=v"(c1) : "v"(e2), "v"(e3));     \
        asm("v_cvt_pk_bf16_f32 %0, %1, %2" : "=v"(c2) : "v"(e4), "v"(e5));     \
        asm("v_cvt_pk_bf16_f32 %0, %1, %2" : "=v"(c3) : "v"(e6), "v"(e7));     \
        swap32(c0, c2); swap32(c1, c3);                                        \
        u32x4 lo_; lo_[0] = c0; lo_[1] = c1; lo_[2] = c2; lo_[3] = c3;         \
        PLO = __builtin_bit_cast(short8, lo_);                                 \
        unsigned int d0, d1, d2, d3;                                           \
        asm("v_cvt_pk_bf16_f32 %0, %1, %2" : "=v"(d0) : "v"(e8), "v"(e9));     \
        asm("v_cvt_pk_bf16_f32 %0, %1, %2" : "=v"(d1) : "v"(e10), "v"(e11));   \
        asm("v_cvt_pk_bf16_f32 %0, %1, %2" : "=v"(d2) : "v"(e12), "v"(e13));   \
        asm("v_cvt_pk_bf16_f32 %0, %1, %2" : "=v"(d3) : "v"(e14), "v"(e15));   \
        swap32(d0, d2); swap32(d1, d3);                                        \
        u32x4 hi_; hi_[0] = d0; hi_[1] = d1; hi_[2] = d2; hi_[3] = d3;         \
        PHI = __builtin_bit_cast(short8, hi_);                                 \
    }

    for (int t = 0; t < 64; ++t) {
        const int tn = ((t + 1) & 63) * 64;
        // ---- swapped QK^T: D[key][q] ----
        f32x16 dd0 = __builtin_amdgcn_mfma_f32_32x32x16_bf16(kf00, qf0, z16, 0, 0, 0);
        dd0 = __builtin_amdgcn_mfma_f32_32x32x16_bf16(kf01, qf1, dd0, 0, 0, 0);
        f32x16 dd1 = __builtin_amdgcn_mfma_f32_32x32x16_bf16(kf10, qf0, z16, 0, 0, 0);
        dd1 = __builtin_amdgcn_mfma_f32_32x32x16_bf16(kf11, qf1, dd1, 0, 0, 0);
        // reload K for next tile (anti-dep: ~1 full tile of slack)
        kf00 = *(const short8*)(kb + (size_t)(tn + l31) * 64 + 32 + 8 * l5);
        kf01 = *(const short8*)(kb + (size_t)(tn + l31) * 64 + 32 + 16 + 8 * l5);
        kf10 = *(const short8*)(kb + (size_t)(tn + 32 + l31) * 64 + 32 + 8 * l5);
        kf11 = *(const short8*)(kb + (size_t)(tn + 32 + l31) * 64 + 32 + 16 + 8 * l5);

        // ---- keys [0,32): softmax-numerator then PV, V reloaded after use --
        short8 pa0, pa1;
        EXPPACK(dd0, pa0, pa1)
        acc0 = __builtin_amdgcn_mfma_f32_32x32x16_bf16(pa0, vf0[0], acc0, 0, 0, 0);
        acc1 = __builtin_amdgcn_mfma_f32_32x32x16_bf16(pa0, vf1[0], acc1, 0, 0, 0);
        acc2 = __builtin_amdgcn_mfma_f32_32x32x16_bf16(pa0, vf2[0], acc2, 0, 0, 0);
        acc3 = __builtin_amdgcn_mfma_f32_32x32x16_bf16(pa0, vf3[0], acc3, 0, 0, 0);
        vf0[0] = *(const short8*)(vr0 + tn);
        vf1[0] = *(const short8*)(vr1 + tn);
        vf2[0] = *(const short8*)(vr2 + tn);
        vf3[0] = *(const short8*)(vr3 + tn);
        acc0 = __builtin_amdgcn_mfma_f32_32x32x16_bf16(pa1, vf0[1], acc0, 0, 0, 0);
        acc1 = __builtin_amdgcn_mfma_f32_32x32x16_bf16(pa1, vf1[1], acc1, 0, 0, 0);
        acc2 = __builtin_amdgcn_mfma_f32_32x32x16_bf16(pa1, vf2[1], acc2, 0, 0, 0);
        acc3 = __builtin_amdgcn_mfma_f32_32x32x16_bf16(pa1, vf3[1], acc3, 0, 0, 0);
        vf0[1] = *(const short8*)(vr0 + tn + 16);
        vf1[1] = *(const short8*)(vr1 + tn + 16);
        vf2[1] = *(const short8*)(vr2 + tn + 16);
        vf3[1] = *(const short8*)(vr3 + tn + 16);

        // ---- keys [32,64) ----
        short8 pa2, pa3;
        EXPPACK(dd1, pa2, pa3)
        acc0 = __builtin_amdgcn_mfma_f32_32x32x16_bf16(pa2, vf0[2], acc0, 0, 0, 0);
        acc1 = __builtin_amdgcn_mfma_f32_32x32x16_bf16(pa2, vf1[2], acc1, 0, 0, 0);
        acc2 = __builtin_amdgcn_mfma_f32_32x32x16_bf16(pa2, vf2[2], acc2, 0, 0, 0);
        acc3 = __builtin_amdgcn_mfma_f32_32x32x16_bf16(pa2, vf3[2], acc3, 0, 0, 0);
        vf0[2] = *(const short8*)(vr0 + tn + 32);
        vf1[2] = *(const short8*)(vr1 + tn + 32);
        vf2[2] = *(const short8*)(vr2 + tn + 32);
        vf3[2] = *(const short8*)(vr3 + tn + 32);
        acc0 = __builtin_amdgcn_mfma_f32_32x32x16_bf16(pa3, vf0[3], acc0, 0, 0, 0);
        acc1 = __builtin_amdgcn_mfma_f32_32x32x16_bf16(pa3, vf1[3], acc1, 0, 0, 0);
        acc2 = __builtin_amdgcn_mfma_f32_32x32x16_bf16(pa3, vf2[3], acc2, 0, 0, 0);
        acc3 = __builtin_amdgcn_mfma_f32_32x32x16_bf16(pa3, vf3[3], acc3, 0, 0, 0);
        vf0[3] = *(const short8*)(vr0 + tn + 48);
        vf1[3] = *(const short8*)(vr1 + tn + 48);
        vf2[3] = *(const short8*)(vr2 + tn + 48);
        vf3[3] = *(const short8*)(vr3 + tn + 48);
    }
#undef EXPPACK

    // ---- row-sum: lane covers half of q=l31's keys; partner is l^32 ----
    psum += __shfl_xor(psum, 32);
    if (l5 == 0) lsum_lds[32 * w + l31] = psum;
    __syncthreads();

    // ---- epilogue: out = gamma*acc/lsum + x ----
    const float g = gamma[0];
#pragma unroll
    for (int rq = 0; rq < 4; ++rq) {
        // acc D row (q-local) = (r&3) + 8*(r>>2) + 4*l5, r = 4*rq+m
        f32x4 ls = *(const f32x4*)&lsum_lds[32 * w + 8 * rq + 4 * l5];
        f32x4 gi;
#pragma unroll
        for (int m = 0; m < 4; ++m) gi[m] = g / ls[m];
        const int srow = s0 + 32 * w + 8 * rq + 4 * l5;
#pragma unroll
        for (int ct = 0; ct < 4; ++ct) {
            const f32x16& a = (ct == 0) ? acc0 : (ct == 1) ? acc1 : (ct == 2) ? acc2 : acc3;
            size_t off = bx_base + (size_t)(chbase + 32 * ct + l31) * 4096 + srow;
            f32x4 xv = *(const f32x4*)(x + off);
            f32x4 o;
#pragma unroll
            for (int m = 0; m < 4; ++m)
                o[m] = gi[m] * a[4 * rq + m] + xv[m];
            *(f32x4*)(out + off) = o;
        }
    }
}

// ---------------------------------------------------------------------------
extern "C" void kernel_launch(void* const* d_in, const int* in_sizes, int n_in,
                              void* d_out, int out_size, void* d_ws, size_t ws_size,
                              hipStream_t stream) {
    const float* x     = (const float*)d_in[0];
    const float* wqk   = (const float*)d_in[1];
    const float* wv    = (const float*)d_in[2];
    const float* gamma = (const float*)d_in[3];
    float* out = (float*)d_out;

    char* ws = (char*)d_ws;
    unsigned short* W    = (unsigned short*)(ws);                       // 160 KiB
    unsigned short* qkT  = (unsigned short*)(ws + 163840);              // 4 MiB
    unsigned short* xT   = (unsigned short*)(ws + 163840 + 4194304);    // 16 MiB
    unsigned short* vbuf = (unsigned short*)(ws + 163840 + 4194304 + 16777216); // 16 MiB

    hipLaunchKernelGGL(prep_w_kernel,    dim3(320),  dim3(256), 0, stream, wqk, wv, W);
    hipLaunchKernelGGL(transpose_kernel, dim3(2048), dim3(256), 0, stream, x, xT);
    hipLaunchKernelGGL(proj_kernel,      dim3(512),  dim3(256), 0, stream, W, xT, qkT, vbuf);
    hipLaunchKernelGGL(attn_kernel,      dim3(512),  dim3(256), 0, stream, qkT, vbuf, x, gamma, out);
}

// Round 10
// 158.835 us; speedup vs baseline: 2.1083x; 2.0879x over previous
//
#include <hip/hip_runtime.h>

typedef __attribute__((ext_vector_type(4)))  float f32x4;
typedef __attribute__((ext_vector_type(16))) float f32x16;
typedef __attribute__((ext_vector_type(8)))  short short8;
typedef __attribute__((ext_vector_type(4)))  unsigned short u16x4;
typedef __attribute__((ext_vector_type(4)))  unsigned int u32x4;
typedef __attribute__((ext_vector_type(2)))  unsigned int u32x2;

// float -> bf16, round-to-nearest-even
static __device__ __forceinline__ unsigned short f2bf(float f) {
    unsigned int u = __float_as_uint(f);
    unsigned int r = (u + 0x7FFFu + ((u >> 16) & 1u)) >> 16;
    return (unsigned short)r;
}

#if __has_builtin(__builtin_amdgcn_exp2f)
#define EXP2(x) __builtin_amdgcn_exp2f(x)
#else
#define EXP2(x) exp2f(x)
#endif

// value-semantics permlane32 swap (no reference params -> no alloca risk)
static __device__ __forceinline__ u32x2 swap32v(unsigned int a, unsigned int b) {
#if __has_builtin(__builtin_amdgcn_permlane32_swap)
    return __builtin_amdgcn_permlane32_swap(a, b, false, false);
#else
    asm("v_permlane32_swap_b32 %0, %1" : "+v"(a), "+v"(b));
    u32x2 r; r[0] = a; r[1] = b; return r;
#endif
}

// 32^-0.5 * log2(e): q-scale with exp2 conversion folded in
#define SCALE2Q 0.25503487756f

// ---------------------------------------------------------------------------
// Kernel 1: pack weights to bf16. W[320][256]: rows 0..31 = scale2q*w_qk(q),
// rows 32..63 = w_qk(k), rows 64..319 = w_v.
// ---------------------------------------------------------------------------
__global__ void prep_w_kernel(const float* __restrict__ wqk,
                              const float* __restrict__ wv,
                              unsigned short* __restrict__ W) {
    int idx = blockIdx.x * 256 + threadIdx.x;
    int o = idx >> 8, c = idx & 255;
    float v;
    if (o < 64) { v = wqk[o * 256 + c]; if (o < 32) v *= SCALE2Q; }
    else        { v = wv[(o - 64) * 256 + c]; }
    W[idx] = f2bf(v);
}

// ---------------------------------------------------------------------------
// Kernel 2: xT[b][s][c] = bf16(x[b][c][s]).  64x64 tiles via LDS.
// ---------------------------------------------------------------------------
__global__ __launch_bounds__(256) void transpose_kernel(
        const float* __restrict__ x, unsigned short* __restrict__ xT) {
    __shared__ unsigned short tile[64][66];
    int b = blockIdx.x & 7;
    int rem = blockIdx.x >> 3;
    int ct = rem >> 6, st = rem & 63;
    int s0 = st * 64, c0 = ct * 64;
    int tid = threadIdx.x;
    int ss = tid & 63, cq = tid >> 6;
#pragma unroll
    for (int p = 0; p < 16; ++p) {
        int cc = p * 4 + cq;
        float v = x[(size_t)(b * 256 + c0 + cc) * 4096 + s0 + ss];
        tile[ss][cc] = f2bf(v);
    }
    __syncthreads();
#pragma unroll
    for (int p = 0; p < 8; ++p) {
        int idx = p * 256 + tid;
        int sr = idx >> 5, jj = idx & 31;
        unsigned int val = *(const unsigned int*)&tile[sr][jj * 2];
        *(unsigned int*)(xT + (size_t)(b * 4096 + s0 + sr) * 256 + c0 + jj * 2) = val;
    }
}

// ---------------------------------------------------------------------------
// Kernel 3: projection GEMM (MFMA 16x16x32, no LDS).
// ---------------------------------------------------------------------------
__global__ __launch_bounds__(256) void proj_kernel(
        const unsigned short* __restrict__ W,    // [320][256]
        const unsigned short* __restrict__ xT,   // [8][4096][256]
        unsigned short* __restrict__ qkT,        // [8][4096][64]
        unsigned short* __restrict__ vbuf) {     // [8][256][4096]
    const int b  = blockIdx.x & 7;
    const int sb = blockIdx.x >> 3;
    const int s0 = sb * 64;
    const int tid = threadIdx.x;
    const int w = tid >> 6, l = tid & 63;
    const int lg = l >> 4, ll = l & 15;
    const size_t xbase = (size_t)b * 4096 * 256;

    f32x4 acc[5][4];
#pragma unroll
    for (int ot = 0; ot < 5; ++ot)
#pragma unroll
        for (int st = 0; st < 4; ++st) acc[ot][st] = (f32x4)0.0f;

    for (int k0 = 0; k0 < 256; k0 += 32) {
        short8 bf[4], af[5];
#pragma unroll
        for (int st = 0; st < 4; ++st)
            bf[st] = *(const short8*)(xT + xbase + (size_t)(s0 + st * 16 + ll) * 256 + k0 + lg * 8);
#pragma unroll
        for (int ot = 0; ot < 5; ++ot)
            af[ot] = *(const short8*)(W + (size_t)(80 * w + ot * 16 + ll) * 256 + k0 + lg * 8);
#pragma unroll
        for (int ot = 0; ot < 5; ++ot)
#pragma unroll
            for (int st = 0; st < 4; ++st)
                acc[ot][st] = __builtin_amdgcn_mfma_f32_16x16x32_bf16(af[ot], bf[st], acc[ot][st], 0, 0, 0);
    }
#pragma unroll
    for (int ot = 0; ot < 5; ++ot) {
        int o0 = 80 * w + ot * 16 + lg * 4;
#pragma unroll
        for (int st = 0; st < 4; ++st) {
            int s = s0 + st * 16 + ll;
            if (o0 < 64) {
                u16x4 pk;
#pragma unroll
                for (int i = 0; i < 4; ++i) pk[i] = f2bf(acc[ot][st][i]);
                *(u16x4*)(qkT + (size_t)b * 4096 * 64 + (size_t)s * 64 + o0) = pk;
            } else {
#pragma unroll
                for (int i = 0; i < 4; ++i)
                    vbuf[(size_t)b * 256 * 4096 + (size_t)(o0 - 64 + i) * 4096 + s] = f2bf(acc[ot][st][i]);
            }
        }
    }
}

// ---------------------------------------------------------------------------
// Kernel 3b: repack V into MFMA B-fragment order.
// vfrag[((b*8 + ct4)*256 + kf16)*64 + l] = short8 of
//   vbuf[b][32*ct4 + (l&31)][16*kf16 + 8*(l>>5) + j], j=0..7.
// Per-thread 16B contiguous read; fully coalesced 16B writes.
// ---------------------------------------------------------------------------
__global__ __launch_bounds__(256) void repack_v_kernel(
        const unsigned short* __restrict__ vbuf,   // [8][256][4096]
        unsigned short* __restrict__ vfrag) {      // [8][8][256][64][8]
    int idx = blockIdx.x * 256 + threadIdx.x;      // 4096 blocks
    int l    = idx & 63;
    int kf16 = (idx >> 6) & 255;
    int ct4  = (idx >> 14) & 7;
    int b    = idx >> 17;
    int l31 = l & 31, l5 = l >> 5;
    short8 v = *(const short8*)(vbuf + (size_t)b * 256 * 4096
                                + (size_t)(32 * ct4 + l31) * 4096
                                + 16 * kf16 + 8 * l5);
    *(short8*)(vfrag + (size_t)idx * 8) = v;
}

// ---------------------------------------------------------------------------
// Kernel 3c: repack K into MFMA A-fragment order.
// kfrag[((b*128 + t2)*2 + h)*64 + l] = short8 of
//   qkT[b][32*t2 + (l&31)][32 + 16*h + 8*(l>>5) + j], j=0..7.
// ---------------------------------------------------------------------------
__global__ __launch_bounds__(256) void repack_k_kernel(
        const unsigned short* __restrict__ qkT,    // [8][4096][64]
        unsigned short* __restrict__ kfrag) {      // [8][128][2][64][8]
    int idx = blockIdx.x * 256 + threadIdx.x;      // 512 blocks
    int l  = idx & 63;
    int h  = (idx >> 6) & 1;
    int t2 = (idx >> 7) & 127;
    int b  = idx >> 14;
    int l31 = l & 31, l5 = l >> 5;
    short8 v = *(const short8*)(qkT + (size_t)b * 4096 * 64
                                + (size_t)(32 * t2 + l31) * 64
                                + 32 + 16 * h + 8 * l5);
    *(short8*)(kfrag + (size_t)idx * 8) = v;
}

// ---------------------------------------------------------------------------
// Kernel 4: attention, in-register softmax, zero inner barriers, and ALL
// K/V fragment loads COALESCED from pre-swizzled frag buffers (addr =
// base + lane*16B). grid 512 = 8b x 32 q-tiles(128) x 2 ch-halves; 4 waves.
// Wave: 32 q x 128 ch. QK swapped mfma(K,Q) -> exp2 -> cvt_pk+permlane ->
// PV. K/V rolling reload with 1-tile anti-dependency slack.
// ---------------------------------------------------------------------------
__global__ __launch_bounds__(256, 2) void attn_kernel(
        const unsigned short* __restrict__ qkT,   // [8][4096][64] (q|k)
        const unsigned short* __restrict__ kfrag, // [8][128][2][64][8]
        const unsigned short* __restrict__ vfrag, // [8][8][256][64][8]
        const float* __restrict__ x,              // [8][256][4096]
        const float* __restrict__ gamma,
        float* __restrict__ out) {
    __shared__ float lsum_lds[128];

    const int b     = blockIdx.x & 7;        // batch == XCD (L2 pinning)
    const int sb    = (blockIdx.x >> 3) & 31;
    const int chalf = blockIdx.x >> 8;
    const int s0    = sb * 128;
    const int w     = threadIdx.x >> 6;      // 0..3
    const int l     = threadIdx.x & 63;
    const int l5    = l >> 5, l31 = l & 31;

    const size_t qk_base = (size_t)b * 4096 * 64;
    const size_t bx_base = (size_t)b * 256 * 4096;
    const int chbase = 128 * chalf;

    // Q frags (one-time, uncoalesced is fine): col=q=s0+32w+l31, k=8*l5+j
    const unsigned short* qrow = qkT + qk_base + (size_t)(s0 + 32 * w + l31) * 64;
    const short8 qf0 = *(const short8*)(qrow + 8 * l5);
    const short8 qf1 = *(const short8*)(qrow + 16 + 8 * l5);

    // frag base pointers (element units; frag stride = 512 ushorts)
    const unsigned short* kfp = kfrag + (size_t)b * 128 * 2 * 512 + 8 * l;
    const unsigned short* vf0p = vfrag + ((size_t)(b * 8 + chalf * 4 + 0) * 256) * 512 + 8 * l;
    const unsigned short* vf1p = vfrag + ((size_t)(b * 8 + chalf * 4 + 1) * 256) * 512 + 8 * l;
    const unsigned short* vf2p = vfrag + ((size_t)(b * 8 + chalf * 4 + 2) * 256) * 512 + 8 * l;
    const unsigned short* vf3p = vfrag + ((size_t)(b * 8 + chalf * 4 + 3) * 256) * 512 + 8 * l;

    f32x16 acc0 = (f32x16)0.0f, acc1 = (f32x16)0.0f;
    f32x16 acc2 = (f32x16)0.0f, acc3 = (f32x16)0.0f;
    float psum = 0.f;
    const f32x16 z16 = (f32x16)0.0f;

    // K frags for tile 0: index ((2t+kt)*2+h)*512
    short8 kf00 = *(const short8*)(kfp + 0 * 512);
    short8 kf01 = *(const short8*)(kfp + 1 * 512);
    short8 kf10 = *(const short8*)(kfp + 2 * 512);
    short8 kf11 = *(const short8*)(kfp + 3 * 512);
    // V frags for tile 0: keyfrag = 4t+ks
    short8 vf0[4], vf1[4], vf2[4], vf3[4];
#pragma unroll
    for (int ks = 0; ks < 4; ++ks) {
        vf0[ks] = *(const short8*)(vf0p + (size_t)ks * 512);
        vf1[ks] = *(const short8*)(vf1p + (size_t)ks * 512);
        vf2[ks] = *(const short8*)(vf2p + (size_t)ks * 512);
        vf3[ks] = *(const short8*)(vf3p + (size_t)ks * 512);
    }

// exp2 16 regs of DD, pack (cvt_pk), permlane-swap into two PV A-frags.
#define EXPPACK(DD, PLO, PHI)                                                  \
    {                                                                          \
        float e0 = EXP2((DD)[0]),   e1 = EXP2((DD)[1]);                        \
        float e2 = EXP2((DD)[2]),   e3 = EXP2((DD)[3]);                        \
        float e4 = EXP2((DD)[4]),   e5 = EXP2((DD)[5]);                        \
        float e6 = EXP2((DD)[6]),   e7 = EXP2((DD)[7]);                        \
        float e8 = EXP2((DD)[8]),   e9 = EXP2((DD)[9]);                        \
        float e10 = EXP2((DD)[10]), e11 = EXP2((DD)[11]);                      \
        float e12 = EXP2((DD)[12]), e13 = EXP2((DD)[13]);                      \
        float e14 = EXP2((DD)[14]), e15 = EXP2((DD)[15]);                      \
        psum += (((e0 + e1) + (e2 + e3)) + ((e4 + e5) + (e6 + e7)))            \
              + (((e8 + e9) + (e10 + e11)) + ((e12 + e13) + (e14 + e15)));     \
        unsigned int c0, c1, c2, c3;                                           \
        asm("v_cvt_pk_bf16_f32 %0, %1, %2" : "=v"(c0) : "v"(e0), "v"(e1));     \
        asm("v_cvt_pk_bf16_f32 %0, %1, %2" : "=v"(c1) : "v"(e2), "v"(e3));     \
        asm("v_cvt_pk_bf16_f32 %0, %1, %2" : "=v"(c2) : "v"(e4), "v"(e5));     \
        asm("v_cvt_pk_bf16_f32 %0, %1, %2" : "=v"(c3) : "v"(e6), "v"(e7));     \
        u32x2 s0_ = swap32v(c0, c2);                                           \
        u32x2 s1_ = swap32v(c1, c3);                                           \
        u32x4 lo_; lo_[0] = s0_[0]; lo_[1] = s1_[0]; lo_[2] = s0_[1]; lo_[3] = s1_[1]; \
        PLO = __builtin_bit_cast(short8, lo_);                                 \
        unsigned int d0, d1, d2, d3;                                           \
        asm("v_cvt_pk_bf16_f32 %0, %1, %2" : "=v"(d0) : "v"(e8), "v"(e9));     \
        asm("v_cvt_pk_bf16_f32 %0, %1, %2" : "=v"(d1) : "v"(e10), "v"(e11));   \
        asm("v_cvt_pk_bf16_f32 %0, %1, %2" : "=v"(d2) : "v"(e12), "v"(e13));   \
        u32x2 s2_ = swap32v(d0, d2);                                           \
        asm("v_cvt_pk_bf16_f32 %0, %1, %2" : "=v"(d3) : "v"(e14), "v"(e15));   \
        u32x2 s3_ = swap32v(d1, d3);                                           \
        u32x4 hi_; hi_[0] = s2_[0]; hi_[1] = s3_[0]; hi_[2] = s2_[1]; hi_[3] = s3_[1]; \
        PHI = __builtin_bit_cast(short8, hi_);                                 \
    }

    for (int t = 0; t < 64; ++t) {
        const int tn = (t + 1) & 63;
        // ---- swapped QK^T: D[key][q] ----
        f32x16 dd0 = __builtin_amdgcn_mfma_f32_32x32x16_bf16(kf00, qf0, z16, 0, 0, 0);
        dd0 = __builtin_amdgcn_mfma_f32_32x32x16_bf16(kf01, qf1, dd0, 0, 0, 0);
        f32x16 dd1 = __builtin_amdgcn_mfma_f32_32x32x16_bf16(kf10, qf0, z16, 0, 0, 0);
        dd1 = __builtin_amdgcn_mfma_f32_32x32x16_bf16(kf11, qf1, dd1, 0, 0, 0);
        // reload K for next tile (coalesced frag loads, ~1 tile of slack)
        kf00 = *(const short8*)(kfp + (size_t)(4 * tn + 0) * 512);
        kf01 = *(const short8*)(kfp + (size_t)(4 * tn + 1) * 512);
        kf10 = *(const short8*)(kfp + (size_t)(4 * tn + 2) * 512);
        kf11 = *(const short8*)(kfp + (size_t)(4 * tn + 3) * 512);

        // ---- keys [0,32): exp/pack then PV; V reloaded right after use ----
        short8 pa0, pa1;
        EXPPACK(dd0, pa0, pa1)
        acc0 = __builtin_amdgcn_mfma_f32_32x32x16_bf16(pa0, vf0[0], acc0, 0, 0, 0);
        acc1 = __builtin_amdgcn_mfma_f32_32x32x16_bf16(pa0, vf1[0], acc1, 0, 0, 0);
        acc2 = __builtin_amdgcn_mfma_f32_32x32x16_bf16(pa0, vf2[0], acc2, 0, 0, 0);
        acc3 = __builtin_amdgcn_mfma_f32_32x32x16_bf16(pa0, vf3[0], acc3, 0, 0, 0);
        vf0[0] = *(const short8*)(vf0p + (size_t)(4 * tn + 0) * 512);
        vf1[0] = *(const short8*)(vf1p + (size_t)(4 * tn + 0) * 512);
        vf2[0] = *(const short8*)(vf2p + (size_t)(4 * tn + 0) * 512);
        vf3[0] = *(const short8*)(vf3p + (size_t)(4 * tn + 0) * 512);
        acc0 = __builtin_amdgcn_mfma_f32_32x32x16_bf16(pa1, vf0[1], acc0, 0, 0, 0);
        acc1 = __builtin_amdgcn_mfma_f32_32x32x16_bf16(pa1, vf1[1], acc1, 0, 0, 0);
        acc2 = __builtin_amdgcn_mfma_f32_32x32x16_bf16(pa1, vf2[1], acc2, 0, 0, 0);
        acc3 = __builtin_amdgcn_mfma_f32_32x32x16_bf16(pa1, vf3[1], acc3, 0, 0, 0);
        vf0[1] = *(const short8*)(vf0p + (size_t)(4 * tn + 1) * 512);
        vf1[1] = *(const short8*)(vf1p + (size_t)(4 * tn + 1) * 512);
        vf2[1] = *(const short8*)(vf2p + (size_t)(4 * tn + 1) * 512);
        vf3[1] = *(const short8*)(vf3p + (size_t)(4 * tn + 1) * 512);

        // ---- keys [32,64) ----
        short8 pa2, pa3;
        EXPPACK(dd1, pa2, pa3)
        acc0 = __builtin_amdgcn_mfma_f32_32x32x16_bf16(pa2, vf0[2], acc0, 0, 0, 0);
        acc1 = __builtin_amdgcn_mfma_f32_32x32x16_bf16(pa2, vf1[2], acc1, 0, 0, 0);
        acc2 = __builtin_amdgcn_mfma_f32_32x32x16_bf16(pa2, vf2[2], acc2, 0, 0, 0);
        acc3 = __builtin_amdgcn_mfma_f32_32x32x16_bf16(pa2, vf3[2], acc3, 0, 0, 0);
        vf0[2] = *(const short8*)(vf0p + (size_t)(4 * tn + 2) * 512);
        vf1[2] = *(const short8*)(vf1p + (size_t)(4 * tn + 2) * 512);
        vf2[2] = *(const short8*)(vf2p + (size_t)(4 * tn + 2) * 512);
        vf3[2] = *(const short8*)(vf3p + (size_t)(4 * tn + 2) * 512);
        acc0 = __builtin_amdgcn_mfma_f32_32x32x16_bf16(pa3, vf0[3], acc0, 0, 0, 0);
        acc1 = __builtin_amdgcn_mfma_f32_32x32x16_bf16(pa3, vf1[3], acc1, 0, 0, 0);
        acc2 = __builtin_amdgcn_mfma_f32_32x32x16_bf16(pa3, vf2[3], acc2, 0, 0, 0);
        acc3 = __builtin_amdgcn_mfma_f32_32x32x16_bf16(pa3, vf3[3], acc3, 0, 0, 0);
        vf0[3] = *(const short8*)(vf0p + (size_t)(4 * tn + 3) * 512);
        vf1[3] = *(const short8*)(vf1p + (size_t)(4 * tn + 3) * 512);
        vf2[3] = *(const short8*)(vf2p + (size_t)(4 * tn + 3) * 512);
        vf3[3] = *(const short8*)(vf3p + (size_t)(4 * tn + 3) * 512);
    }
#undef EXPPACK

    // ---- row-sum: lane covers half of q=l31's keys; partner is l^32 ----
    psum += __shfl_xor(psum, 32);
    if (l5 == 0) lsum_lds[32 * w + l31] = psum;
    __syncthreads();

    // ---- epilogue: out = gamma*acc/lsum + x (explicit accs, no refs) ----
    const float g = gamma[0];
#pragma unroll
    for (int rq = 0; rq < 4; ++rq) {
        f32x4 ls = *(const f32x4*)&lsum_lds[32 * w + 8 * rq + 4 * l5];
        f32x4 gi;
#pragma unroll
        for (int m = 0; m < 4; ++m) gi[m] = g / ls[m];
        const int srow = s0 + 32 * w + 8 * rq + 4 * l5;
#define STORE_CT(ACC, CT)                                                      \
        {                                                                      \
            size_t off = bx_base + (size_t)(chbase + 32 * (CT) + l31) * 4096 + srow; \
            f32x4 xv = *(const f32x4*)(x + off);                               \
            f32x4 o;                                                           \
            o[0] = gi[0] * (ACC)[4 * rq + 0] + xv[0];                          \
            o[1] = gi[1] * (ACC)[4 * rq + 1] + xv[1];                          \
            o[2] = gi[2] * (ACC)[4 * rq + 2] + xv[2];                          \
            o[3] = gi[3] * (ACC)[4 * rq + 3] + xv[3];                          \
            *(f32x4*)(out + off) = o;                                          \
        }
        STORE_CT(acc0, 0)
        STORE_CT(acc1, 1)
        STORE_CT(acc2, 2)
        STORE_CT(acc3, 3)
#undef STORE_CT
    }
}

// ---------------------------------------------------------------------------
extern "C" void kernel_launch(void* const* d_in, const int* in_sizes, int n_in,
                              void* d_out, int out_size, void* d_ws, size_t ws_size,
                              hipStream_t stream) {
    const float* x     = (const float*)d_in[0];
    const float* wqk   = (const float*)d_in[1];
    const float* wv    = (const float*)d_in[2];
    const float* gamma = (const float*)d_in[3];
    float* out = (float*)d_out;

    char* ws = (char*)d_ws;
    unsigned short* W     = (unsigned short*)(ws);                      // 160 KiB
    unsigned short* qkT   = (unsigned short*)(ws + 163840);             // 4 MiB
    unsigned short* xT    = (unsigned short*)(ws + 163840 + 4194304);   // 16 MiB (-> vfrag after proj)
    unsigned short* vbuf  = (unsigned short*)(ws + 163840 + 4194304 + 16777216); // 16 MiB
    unsigned short* kfrag = (unsigned short*)(ws + 163840 + 4194304 + 16777216 + 16777216); // 2 MiB
    unsigned short* vfrag = xT;   // reuse xT region (dead after proj)

    hipLaunchKernelGGL(prep_w_kernel,    dim3(320),  dim3(256), 0, stream, wqk, wv, W);
    hipLaunchKernelGGL(transpose_kernel, dim3(2048), dim3(256), 0, stream, x, xT);
    hipLaunchKernelGGL(proj_kernel,      dim3(512),  dim3(256), 0, stream, W, xT, qkT, vbuf);
    hipLaunchKernelGGL(repack_v_kernel,  dim3(4096), dim3(256), 0, stream, vbuf, vfrag);
    hipLaunchKernelGGL(repack_k_kernel,  dim3(512),  dim3(256), 0, stream, qkT, kfrag);
    hipLaunchKernelGGL(attn_kernel,      dim3(512),  dim3(256), 0, stream, qkT, kfrag, vfrag, x, gamma, out);
}